// Round 19
// baseline (54.679 us; speedup 1.0000x reference)
//
#include <hip/hip_runtime.h>
#include <hip/hip_bf16.h>

typedef short bf16x8 __attribute__((ext_vector_type(8)));
typedef float f32x4 __attribute__((ext_vector_type(4)));
typedef float f4    __attribute__((ext_vector_type(4)));
typedef unsigned short u16;

#define D_DIM  128
#define S_LEN  16384
#define NBLK   512
#define NTILES 4096      // 262144 rows / 64 rows per block-tile (4 waves x 16 rows)
#define ITERS  8         // NTILES / NBLK

__device__ __forceinline__ u16 f2bf(float f) {
    __hip_bfloat16 h = __float2bfloat16(f);
    return __builtin_bit_cast(u16, h);
}

struct Pre {
    f4   xv[8];   // wave's 16x128 x-tile fragment slice (32 VGPR)
    int4 msk;     // raw mask[row0+g*4 .. +3] (4 VGPR) — NOT consumed at issue time
};

// PURE load issue — no load result is consumed here, so no s_waitcnt is
// generated inside. Call site follows with sched_barrier(0) to pin placement.
__device__ __forceinline__ void prefetch_issue(const float* __restrict__ x,
                                               const int* __restrict__ mask,
                                               int tile, int wv, int ln, int g,
                                               Pre& p) {
    const int row0 = tile * 64 + wv * 16;
    const float* xp = x + (long)(row0 + ln) * D_DIM + g * 8;
#pragma unroll
    for (int kc = 0; kc < 4; ++kc) {
        p.xv[2*kc]   = *(const f4*)(xp + kc*32);
        p.xv[2*kc+1] = *(const f4*)(xp + kc*32 + 4);
    }
    p.msk = *(const int4*)(mask + row0 + g*4);   // aligned 16B, one dwordx4
}

__device__ __forceinline__ void compute_tile(int tile, const Pre& p,
    const u16* __restrict__ w1f, const u16* __restrict__ w2f, u16* __restrict__ hw,
    const float* b1f, const float* b2f,
    float* __restrict__ out, int wv, int l, int ln, int g) {

    const int row0 = tile * 64 + wv * 16;
    const f32x4 zero = {0.f, 0.f, 0.f, 0.f};

    // ---- convert prefetched x to bf16 A-fragments (vmcnt wait lands HERE,
    //      one full tile after issue) ----
    bf16x8 a[4];
#pragma unroll
    for (int kc = 0; kc < 4; ++kc) {
        const f4 lo = p.xv[2*kc], hi = p.xv[2*kc+1];
        bf16x8 t;
        t[0]=(short)f2bf(lo[0]); t[1]=(short)f2bf(lo[1]); t[2]=(short)f2bf(lo[2]); t[3]=(short)f2bf(lo[3]);
        t[4]=(short)f2bf(hi[0]); t[5]=(short)f2bf(hi[1]); t[6]=(short)f2bf(hi[2]); t[7]=(short)f2bf(hi[3]);
        a[kc] = t;
    }

    // ---- mask + hard-reset decay factors (deferred from prefetch) ----
    float mfac[4];
    {
        const int mr[4] = {p.msk.x, p.msk.y, p.msk.z, p.msk.w};
#pragma unroll
        for (int r = 0; r < 4; ++r) {
            const int fr = row0 + g*4 + r;
            const unsigned s = (unsigned)(fr & (S_LEN - 1));
            const float sc = (((s + 1u) % 10u) == 0u) ? 0.1f : 1.0f;
            mfac[r] = mr[r] ? sc : 0.0f;
        }
    }

    // ---- layer 1: H = X @ W1 — frag-layout LDS reads (conflict-free) ----
    f32x4 acc1[8];
#pragma unroll
    for (int ct = 0; ct < 8; ++ct) acc1[ct] = zero;
#pragma unroll
    for (int kc = 0; kc < 4; ++kc) {
#pragma unroll
        for (int ct = 0; ct < 8; ++ct) {
            const bf16x8 b = *(const bf16x8*)&w1f[(kc*8 + ct)*512 + l*8];
            acc1[ct] = __builtin_amdgcn_mfma_f32_16x16x32_bf16(a[kc], b, acc1[ct], 0, 0, 0);
        }
    }

    // ---- bias + silu -> h to per-wave LDS (swizzled, true-column layout) ----
#pragma unroll
    for (int hh = 0; hh < 2; ++hh) {
#pragma unroll
        for (int r = 0; r < 4; ++r) {
            const int row = g*4 + r;
            float z0 = acc1[hh*4+0][r] + b1f[hh*4+0];
            float z1 = acc1[hh*4+1][r] + b1f[hh*4+1];
            float z2 = acc1[hh*4+2][r] + b1f[hh*4+2];
            float z3 = acc1[hh*4+3][r] + b1f[hh*4+3];
            ushort4 pk;
            pk.x = f2bf(z0 / (1.f + __expf(-z0)));
            pk.y = f2bf(z1 / (1.f + __expf(-z1)));
            pk.z = f2bf(z2 / (1.f + __expf(-z2)));
            pk.w = f2bf(z3 / (1.f + __expf(-z3)));
            const int c0  = hh*64 + 4*ln;
            const int idx = row*128 + (((c0 >> 3) ^ (row & 7)) << 3) + (c0 & 7);
            *(ushort4*)&hw[idx] = pk;
        }
    }

    // ---- read h A-fragments (same-wave LDS round trip, no barrier) ----
    bf16x8 ha[4];
#pragma unroll
    for (int kc = 0; kc < 4; ++kc) {
        const int u = kc*4 + g;
        ha[kc] = *(const bf16x8*)&hw[ln*128 + ((u ^ (ln & 7)) << 3)];
    }

    // ---- layer 2: Y = H @ W2 — frag-layout LDS reads ----
    f32x4 acc2[8];
#pragma unroll
    for (int ct = 0; ct < 8; ++ct) acc2[ct] = zero;
#pragma unroll
    for (int kc = 0; kc < 4; ++kc) {
#pragma unroll
        for (int ct = 0; ct < 8; ++ct) {
            const bf16x8 b = *(const bf16x8*)&w2f[(kc*8 + ct)*512 + l*8];
            acc2[ct] = __builtin_amdgcn_mfma_f32_16x16x32_bf16(ha[kc], b, acc2[ct], 0, 0, 0);
        }
    }

    // ---- DIRECT epilogue: bias + mask/decay, nt f4 stores straight from acc2 ----
#pragma unroll
    for (int r = 0; r < 4; ++r) {
        const int row = g*4 + r;
        float* op = out + (long)(row0 + row) * D_DIM + 4*ln;
#pragma unroll
        for (int hh = 0; hh < 2; ++hh) {
            f4 f;
            f[0] = (acc2[hh*4+0][r] + b2f[hh*4+0]) * mfac[r];
            f[1] = (acc2[hh*4+1][r] + b2f[hh*4+1]) * mfac[r];
            f[2] = (acc2[hh*4+2][r] + b2f[hh*4+2]) * mfac[r];
            f[3] = (acc2[hh*4+3][r] + b2f[hh*4+3]) * mfac[r];
            __builtin_nontemporal_store(f, (f4*)(op + hh*64));
        }
    }
}

__global__ void __launch_bounds__(256, 2)
ssm_fused_v19(const float* __restrict__ x,
              const int*   __restrict__ mask,
              const float* __restrict__ W1,
              const float* __restrict__ b1,
              const float* __restrict__ W2,
              const float* __restrict__ b2,
              float* __restrict__ out) {
    // LDS: weight frags (64 KiB) + h (16 KiB) = 80 KiB -> 2 blocks/CU
    __shared__ __align__(16) u16 wlds[2*16384];
    __shared__ __align__(16) u16 hlds[4*16*128];

    const int tid = threadIdx.x;
    const int l   = tid & 63;
    const int ln  = tid & 15;
    const int g   = (tid >> 4) & 3;
    const int wv  = tid >> 6;

    // ---- stage W1,W2 as bf16 directly in MFMA FRAG LAYOUT (fused prep) ----
    for (int i = tid; i < 4096; i += 256) {
        int k  = i >> 5;
        int n0 = (i & 31) * 4;
        float4 v1 = *(const float4*)(W1 + k*128 + n0);
        float4 v2 = *(const float4*)(W2 + k*128 + n0);
        const float* p1 = (const float*)&v1;
        const float* p2 = (const float*)&v2;
        const int kc = k >> 5;
        const int gg = (k >> 3) & 3;
        const int j  = k & 7;
#pragma unroll
        for (int jj = 0; jj < 4; ++jj) {
            const int col = n0 + jj;
            const int ct  = ((col >> 6) << 2) + (col & 3);
            const int lnn = (col & 63) >> 2;
            const int idx = (kc*8 + ct)*512 + (gg*16 + lnn)*8 + j;
            wlds[idx]         = f2bf(p1[jj]);
            wlds[16384 + idx] = f2bf(p2[jj]);
        }
    }
    __syncthreads();

    const u16* w1f = wlds;            // frag f at u16 offset f*512 + l*8
    const u16* w2f = wlds + 16384;

    // per-lane bias fragments at permuted columns
    float b1f[8], b2f[8];
#pragma unroll
    for (int ct = 0; ct < 8; ++ct) {
        const int col = (ct >> 2)*64 + (ct & 3) + 4*ln;
        b1f[ct] = b1[col];
        b2f[ct] = b2[col];
    }

    u16* hw = hlds + wv * 2048;

    // ---- software-pipelined main loop (ping-pong Pre, pinned PURE-load issue) ----
    Pre pa, pb;
    prefetch_issue(x, mask, blockIdx.x, wv, ln, g, pa);
    __builtin_amdgcn_sched_barrier(0);

#pragma unroll 1
    for (int itp = 0; itp < ITERS/2; ++itp) {
        const int tA = blockIdx.x + (2*itp) * NBLK;
        const int tB = tA + NBLK;
        int tC = tB + NBLK; if (tC >= NTILES) tC = tB;

        prefetch_issue(x, mask, tB, wv, ln, g, pb);
        __builtin_amdgcn_sched_barrier(0);
        compute_tile(tA, pa, w1f, w2f, hw, b1f, b2f, out, wv, l, ln, g);

        prefetch_issue(x, mask, tC, wv, ln, g, pa);
        __builtin_amdgcn_sched_barrier(0);
        compute_tile(tB, pb, w1f, w2f, hw, b1f, b2f, out, wv, l, ln, g);
    }
}

extern "C" void kernel_launch(void* const* d_in, const int* in_sizes, int n_in,
                              void* d_out, int out_size, void* d_ws, size_t ws_size,
                              hipStream_t stream) {
    const float* x    = (const float*)d_in[0];
    const int*   mask = (const int*)d_in[1];
    const float* W1   = (const float*)d_in[2];
    const float* b1   = (const float*)d_in[3];
    const float* W2   = (const float*)d_in[4];
    const float* b2   = (const float*)d_in[5];
    float* out = (float*)d_out;

    hipLaunchKernelGGL(ssm_fused_v19, dim3(NBLK), dim3(256), 0, stream,
                       x, mask, W1, b1, W2, b2, out);
}

// Round 20
// 54.545 us; speedup vs baseline: 1.0025x; 1.0025x over previous
//
#include <hip/hip_runtime.h>
#include <hip/hip_bf16.h>

typedef short bf16x8 __attribute__((ext_vector_type(8)));
typedef float f32x4 __attribute__((ext_vector_type(4)));
typedef float f4    __attribute__((ext_vector_type(4)));
typedef unsigned short u16;

#define D_DIM  128
#define S_LEN  16384
#define NBLK   512
#define NTILES 4096      // 262144 rows / 64 rows per block-tile (4 waves x 16 rows)
#define ITERS  8         // NTILES / NBLK

__device__ __forceinline__ u16 f2bf(float f) {
    __hip_bfloat16 h = __float2bfloat16(f);
    return __builtin_bit_cast(u16, h);
}

struct Pre {
    f4   xv[8];   // wave's 16x128 x-tile fragment slice (32 VGPR)
    int4 msk;     // raw mask[row0+g*4 .. +3] (4 VGPR)
};

// PURE load issue — no load result consumed here. Call site follows with
// sched_barrier(0) to pin placement.
__device__ __forceinline__ void prefetch_issue(const float* __restrict__ x,
                                               const int* __restrict__ mask,
                                               int tile, int wv, int ln, int g,
                                               Pre& p) {
    const int row0 = tile * 64 + wv * 16;
    const float* xp = x + (long)(row0 + ln) * D_DIM + g * 8;
#pragma unroll
    for (int kc = 0; kc < 4; ++kc) {
        p.xv[2*kc]   = *(const f4*)(xp + kc*32);
        p.xv[2*kc+1] = *(const f4*)(xp + kc*32 + 4);
    }
    p.msk = *(const int4*)(mask + row0 + g*4);   // aligned 16B, one dwordx4
}

__device__ __forceinline__ void compute_tile(int tile, const Pre& p,
    const u16* __restrict__ w1f, const u16* __restrict__ w2f, u16* __restrict__ hw,
    const float* b1f, const float* b2f,
    float* __restrict__ out, int wv, int l, int ln, int g) {

    const int row0 = tile * 64 + wv * 16;
    const f32x4 zero = {0.f, 0.f, 0.f, 0.f};

    // ---- convert prefetched x to bf16 A-fragments ----
    bf16x8 a[4];
#pragma unroll
    for (int kc = 0; kc < 4; ++kc) {
        const f4 lo = p.xv[2*kc], hi = p.xv[2*kc+1];
        bf16x8 t;
        t[0]=(short)f2bf(lo[0]); t[1]=(short)f2bf(lo[1]); t[2]=(short)f2bf(lo[2]); t[3]=(short)f2bf(lo[3]);
        t[4]=(short)f2bf(hi[0]); t[5]=(short)f2bf(hi[1]); t[6]=(short)f2bf(hi[2]); t[7]=(short)f2bf(hi[3]);
        a[kc] = t;
    }

    // ---- mask + hard-reset decay factors ----
    float mfac[4];
    {
        const int mr[4] = {p.msk.x, p.msk.y, p.msk.z, p.msk.w};
#pragma unroll
        for (int r = 0; r < 4; ++r) {
            const int fr = row0 + g*4 + r;
            const unsigned s = (unsigned)(fr & (S_LEN - 1));
            const float sc = (((s + 1u) % 10u) == 0u) ? 0.1f : 1.0f;
            mfac[r] = mr[r] ? sc : 0.0f;
        }
    }

    // ---- layer 1: H = X @ W1 — frag-layout LDS reads (conflict-free).
    //      setprio(1): waves in their MFMA cluster win issue arbitration over
    //      waves doing prefetch/convert (no barriers -> phases are diverse). ----
    f32x4 acc1[8];
#pragma unroll
    for (int ct = 0; ct < 8; ++ct) acc1[ct] = zero;
    __builtin_amdgcn_s_setprio(1);
#pragma unroll
    for (int kc = 0; kc < 4; ++kc) {
#pragma unroll
        for (int ct = 0; ct < 8; ++ct) {
            const bf16x8 b = *(const bf16x8*)&w1f[(kc*8 + ct)*512 + l*8];
            acc1[ct] = __builtin_amdgcn_mfma_f32_16x16x32_bf16(a[kc], b, acc1[ct], 0, 0, 0);
        }
    }
    __builtin_amdgcn_s_setprio(0);

    // ---- bias + silu -> h to per-wave LDS (swizzled, true-column layout) ----
#pragma unroll
    for (int hh = 0; hh < 2; ++hh) {
#pragma unroll
        for (int r = 0; r < 4; ++r) {
            const int row = g*4 + r;
            float z0 = acc1[hh*4+0][r] + b1f[hh*4+0];
            float z1 = acc1[hh*4+1][r] + b1f[hh*4+1];
            float z2 = acc1[hh*4+2][r] + b1f[hh*4+2];
            float z3 = acc1[hh*4+3][r] + b1f[hh*4+3];
            ushort4 pk;
            pk.x = f2bf(z0 / (1.f + __expf(-z0)));
            pk.y = f2bf(z1 / (1.f + __expf(-z1)));
            pk.z = f2bf(z2 / (1.f + __expf(-z2)));
            pk.w = f2bf(z3 / (1.f + __expf(-z3)));
            const int c0  = hh*64 + 4*ln;
            const int idx = row*128 + (((c0 >> 3) ^ (row & 7)) << 3) + (c0 & 7);
            *(ushort4*)&hw[idx] = pk;
        }
    }

    // ---- read h A-fragments (same-wave LDS round trip, no barrier) ----
    bf16x8 ha[4];
#pragma unroll
    for (int kc = 0; kc < 4; ++kc) {
        const int u = kc*4 + g;
        ha[kc] = *(const bf16x8*)&hw[ln*128 + ((u ^ (ln & 7)) << 3)];
    }

    // ---- layer 2: Y = H @ W2 — frag-layout LDS reads ----
    f32x4 acc2[8];
#pragma unroll
    for (int ct = 0; ct < 8; ++ct) acc2[ct] = zero;
    __builtin_amdgcn_s_setprio(1);
#pragma unroll
    for (int kc = 0; kc < 4; ++kc) {
#pragma unroll
        for (int ct = 0; ct < 8; ++ct) {
            const bf16x8 b = *(const bf16x8*)&w2f[(kc*8 + ct)*512 + l*8];
            acc2[ct] = __builtin_amdgcn_mfma_f32_16x16x32_bf16(ha[kc], b, acc2[ct], 0, 0, 0);
        }
    }
    __builtin_amdgcn_s_setprio(0);

    // ---- DIRECT epilogue: bias + mask/decay, nt f4 stores straight from acc2 ----
#pragma unroll
    for (int r = 0; r < 4; ++r) {
        const int row = g*4 + r;
        float* op = out + (long)(row0 + row) * D_DIM + 4*ln;
#pragma unroll
        for (int hh = 0; hh < 2; ++hh) {
            f4 f;
            f[0] = (acc2[hh*4+0][r] + b2f[hh*4+0]) * mfac[r];
            f[1] = (acc2[hh*4+1][r] + b2f[hh*4+1]) * mfac[r];
            f[2] = (acc2[hh*4+2][r] + b2f[hh*4+2]) * mfac[r];
            f[3] = (acc2[hh*4+3][r] + b2f[hh*4+3]) * mfac[r];
            __builtin_nontemporal_store(f, (f4*)(op + hh*64));
        }
    }
}

__global__ void __launch_bounds__(256, 2)
ssm_fused_v20(const float* __restrict__ x,
              const int*   __restrict__ mask,
              const float* __restrict__ W1,
              const float* __restrict__ b1,
              const float* __restrict__ W2,
              const float* __restrict__ b2,
              float* __restrict__ out) {
    // LDS: weight frags (64 KiB) + h (16 KiB) = 80 KiB -> 2 blocks/CU
    __shared__ __align__(16) u16 wlds[2*16384];
    __shared__ __align__(16) u16 hlds[4*16*128];

    const int tid = threadIdx.x;
    const int l   = tid & 63;
    const int ln  = tid & 15;
    const int g   = (tid >> 4) & 3;
    const int wv  = tid >> 6;

    // ---- stage W1,W2 as bf16 directly in MFMA FRAG LAYOUT (fused prep) ----
    for (int i = tid; i < 4096; i += 256) {
        int k  = i >> 5;
        int n0 = (i & 31) * 4;
        float4 v1 = *(const float4*)(W1 + k*128 + n0);
        float4 v2 = *(const float4*)(W2 + k*128 + n0);
        const float* p1 = (const float*)&v1;
        const float* p2 = (const float*)&v2;
        const int kc = k >> 5;
        const int gg = (k >> 3) & 3;
        const int j  = k & 7;
#pragma unroll
        for (int jj = 0; jj < 4; ++jj) {
            const int col = n0 + jj;
            const int ct  = ((col >> 6) << 2) + (col & 3);
            const int lnn = (col & 63) >> 2;
            const int idx = (kc*8 + ct)*512 + (gg*16 + lnn)*8 + j;
            wlds[idx]         = f2bf(p1[jj]);
            wlds[16384 + idx] = f2bf(p2[jj]);
        }
    }
    __syncthreads();

    const u16* w1f = wlds;            // frag f at u16 offset f*512 + l*8
    const u16* w2f = wlds + 16384;

    // per-lane bias fragments at permuted columns
    float b1f[8], b2f[8];
#pragma unroll
    for (int ct = 0; ct < 8; ++ct) {
        const int col = (ct >> 2)*64 + (ct & 3) + 4*ln;
        b1f[ct] = b1[col];
        b2f[ct] = b2[col];
    }

    u16* hw = hlds + wv * 2048;

    // ---- software-pipelined main loop (ping-pong Pre, pinned PURE-load issue) ----
    Pre pa, pb;
    prefetch_issue(x, mask, blockIdx.x, wv, ln, g, pa);
    __builtin_amdgcn_sched_barrier(0);

#pragma unroll 1
    for (int itp = 0; itp < ITERS/2; ++itp) {
        const int tA = blockIdx.x + (2*itp) * NBLK;
        const int tB = tA + NBLK;
        int tC = tB + NBLK; if (tC >= NTILES) tC = tB;

        prefetch_issue(x, mask, tB, wv, ln, g, pb);
        __builtin_amdgcn_sched_barrier(0);
        compute_tile(tA, pa, w1f, w2f, hw, b1f, b2f, out, wv, l, ln, g);

        prefetch_issue(x, mask, tC, wv, ln, g, pa);
        __builtin_amdgcn_sched_barrier(0);
        compute_tile(tB, pb, w1f, w2f, hw, b1f, b2f, out, wv, l, ln, g);
    }
}

extern "C" void kernel_launch(void* const* d_in, const int* in_sizes, int n_in,
                              void* d_out, int out_size, void* d_ws, size_t ws_size,
                              hipStream_t stream) {
    const float* x    = (const float*)d_in[0];
    const int*   mask = (const int*)d_in[1];
    const float* W1   = (const float*)d_in[2];
    const float* b1   = (const float*)d_in[3];
    const float* W2   = (const float*)d_in[4];
    const float* b2   = (const float*)d_in[5];
    float* out = (float*)d_out;

    hipLaunchKernelGGL(ssm_fused_v20, dim3(NBLK), dim3(256), 0, stream,
                       x, mask, W1, b1, W2, b2, out);
}